// Round 1
// baseline (218.751 us; speedup 1.0000x reference)
//
#include <hip/hip_runtime.h>

// RotatedGridPool: B=4, C=256, H=200, W=176, N=128, G=7
// Output: (B*N, C, G, G) fp32.
//
// One block per (b,n) ROI. Threads 0..48 precompute bilinear sample data
// (4 weights with zero-padding validity folded in, 4 clamped flat offsets)
// into LDS; then block-stride loop over C*49 output elements with
// e = c*49 + pt so global writes are fully coalesced.

constexpr int Bc = 4;
constexpr int Cc = 256;
constexpr int Hc = 200;
constexpr int Wc = 176;
constexpr int Nc = 128;
constexpr int G  = 7;
constexpr int NPTS = G * G;          // 49
constexpr float MIN_Xf = 0.0f;
constexpr float MIN_Yf = -40.0f;

__global__ __launch_bounds__(256) void rot_grid_pool_kernel(
    const float* __restrict__ feat,       // (B,C,H,W)
    const float* __restrict__ rois,       // (B,N,7)
    const float* __restrict__ voxel_size, // (2,)
    const int*   __restrict__ fms,        // scalar stride
    float* __restrict__ out)              // (B*N, C, G, G)
{
    const int bn = blockIdx.x;            // 0 .. B*N-1
    const int b  = bn / Nc;

    // ---- per-ROI affine theta (all threads redundantly; cheap) ----
    const float* roi = rois + (size_t)bn * 7;
    const float cx = roi[0], cy = roi[1];
    const float dx = roi[3], dy = roi[4];
    const float ang = roi[6];
    const float stride = (float)fms[0];
    const float vx = voxel_size[0] * stride;
    const float vy = voxel_size[1] * stride;

    const float x1 = (cx - dx * 0.5f - MIN_Xf) / vx;
    const float x2 = (cx + dx * 0.5f - MIN_Xf) / vx;
    const float y1 = (cy - dy * 0.5f - MIN_Yf) / vy;
    const float y2 = (cy + dy * 0.5f - MIN_Yf) / vy;

    float sina, cosa;
    __sincosf(ang, &sina, &cosa);

    const float wm1 = (float)(Wc - 1);
    const float hm1 = (float)(Hc - 1);
    const float scale1 = (y2 - y1) / fmaxf(x2 - x1, 0.01f);
    const float scale2 = (x2 - x1) / fmaxf(y2 - y1, 0.01f);
    const float t00 = (x2 - x1) / wm1 * cosa;
    const float t01 = (x2 - x1) / wm1 * (-sina) * scale1;
    const float t02 = (x1 + x2 - wm1) / wm1;
    const float t10 = (y2 - y1) / hm1 * sina * scale2;
    const float t11 = (y2 - y1) / hm1 * cosa;
    const float t12 = (y1 + y2 - hm1) / hm1;

    // ---- per-point bilinear data into LDS ----
    __shared__ int   s_o00[NPTS], s_o01[NPTS], s_o10[NPTS], s_o11[NPTS];
    __shared__ float s_w00[NPTS], s_w01[NPTS], s_w10[NPTS], s_w11[NPTS];

    const int tid = threadIdx.x;
    if (tid < NPTS) {
        const int row = tid / G;
        const int col = tid - row * G;
        // affine_grid base coords, align_corners=False
        const float xx = (2.0f * (float)col + 1.0f) / (float)G - 1.0f;
        const float yy = (2.0f * (float)row + 1.0f) / (float)G - 1.0f;
        const float gx = t00 * xx + t01 * yy + t02;
        const float gy = t10 * xx + t11 * yy + t12;
        // grid_sample unnormalize, align_corners=False
        const float ix = ((gx + 1.0f) * (float)Wc - 1.0f) * 0.5f;
        const float iy = ((gy + 1.0f) * (float)Hc - 1.0f) * 0.5f;

        const float x0f = floorf(ix);
        const float y0f = floorf(iy);
        const float x1f = x0f + 1.0f;
        const float y1f = y0f + 1.0f;
        const float wx1 = ix - x0f, wx0 = 1.0f - wx1;
        const float wy1 = iy - y0f, wy0 = 1.0f - wy1;

        const float vx0 = (x0f >= 0.0f && x0f <= wm1) ? 1.0f : 0.0f;
        const float vx1 = (x1f >= 0.0f && x1f <= wm1) ? 1.0f : 0.0f;
        const float vy0 = (y0f >= 0.0f && y0f <= hm1) ? 1.0f : 0.0f;
        const float vy1 = (y1f >= 0.0f && y1f <= hm1) ? 1.0f : 0.0f;

        const int xc0 = (int)fminf(fmaxf(x0f, 0.0f), wm1);
        const int xc1 = (int)fminf(fmaxf(x1f, 0.0f), wm1);
        const int yc0 = (int)fminf(fmaxf(y0f, 0.0f), hm1);
        const int yc1 = (int)fminf(fmaxf(y1f, 0.0f), hm1);

        s_o00[tid] = yc0 * Wc + xc0;
        s_o01[tid] = yc0 * Wc + xc1;
        s_o10[tid] = yc1 * Wc + xc0;
        s_o11[tid] = yc1 * Wc + xc1;
        s_w00[tid] = wy0 * wx0 * vy0 * vx0;
        s_w01[tid] = wy0 * wx1 * vy0 * vx1;
        s_w10[tid] = wy1 * wx0 * vy1 * vx0;
        s_w11[tid] = wy1 * wx1 * vy1 * vx1;
    }
    __syncthreads();

    // ---- main loop: C*49 elements, coalesced writes ----
    const float* __restrict__ fb = feat + (size_t)b * Cc * Hc * Wc;
    float* __restrict__ ob = out + (size_t)bn * Cc * NPTS;

    for (int e = tid; e < Cc * NPTS; e += 256) {
        const int c  = e / NPTS;
        const int pt = e - c * NPTS;
        const float* __restrict__ fc = fb + (size_t)c * (Hc * Wc);
        const float v = s_w00[pt] * fc[s_o00[pt]]
                      + s_w01[pt] * fc[s_o01[pt]]
                      + s_w10[pt] * fc[s_o10[pt]]
                      + s_w11[pt] * fc[s_o11[pt]];
        ob[e] = v;
    }
}

extern "C" void kernel_launch(void* const* d_in, const int* in_sizes, int n_in,
                              void* d_out, int out_size, void* d_ws, size_t ws_size,
                              hipStream_t stream) {
    const float* feat = (const float*)d_in[0];
    const float* rois = (const float*)d_in[1];
    const float* vox  = (const float*)d_in[2];
    const int*   fms  = (const int*)d_in[3];
    float* out = (float*)d_out;

    rot_grid_pool_kernel<<<dim3(Bc * Nc), dim3(256), 0, stream>>>(
        feat, rois, vox, fms, out);
}

// Round 2
// 215.223 us; speedup vs baseline: 1.0164x; 1.0164x over previous
//
#include <hip/hip_runtime.h>

// RotatedGridPool: B=4, C=256, H=200, W=176, N=128, G=7
// Output: (B*N, C, G, G) fp32.
//
// R2: latency-bound fix — split channels across 8 blocks per ROI:
// grid = (B*N, 8), each block does 32 channels x 49 pts = 1568 elements
// with a fully-unrolled 7-iteration loop (28 gather loads in flight).
// Occupancy 8 -> 32 waves/CU.

constexpr int Bc = 4;
constexpr int Cc = 256;
constexpr int Hc = 200;
constexpr int Wc = 176;
constexpr int Nc = 128;
constexpr int G  = 7;
constexpr int NPTS = G * G;          // 49
constexpr int CSPLIT = 8;            // blocks per ROI
constexpr int CCHUNK = Cc / CSPLIT;  // 32 channels per block
constexpr int ELEMS  = CCHUNK * NPTS; // 1568
constexpr float MIN_Xf = 0.0f;
constexpr float MIN_Yf = -40.0f;

__global__ __launch_bounds__(256, 8) void rot_grid_pool_kernel(
    const float* __restrict__ feat,       // (B,C,H,W)
    const float* __restrict__ rois,       // (B,N,7)
    const float* __restrict__ voxel_size, // (2,)
    const int*   __restrict__ fms,        // scalar stride
    float* __restrict__ out)              // (B*N, C, G, G)
{
    const int bn    = blockIdx.x;         // 0 .. B*N-1
    const int chunk = blockIdx.y;         // 0 .. CSPLIT-1
    const int b     = bn / Nc;

    // ---- per-point bilinear data into LDS ----
    __shared__ int   s_o00[NPTS], s_o01[NPTS], s_o10[NPTS], s_o11[NPTS];
    __shared__ float s_w00[NPTS], s_w01[NPTS], s_w10[NPTS], s_w11[NPTS];

    const int tid = threadIdx.x;
    if (tid < NPTS) {
        // ---- per-ROI affine theta ----
        const float* roi = rois + (size_t)bn * 7;
        const float cx = roi[0], cy = roi[1];
        const float dx = roi[3], dy = roi[4];
        const float ang = roi[6];
        const float stride = (float)fms[0];
        const float vx = voxel_size[0] * stride;
        const float vy = voxel_size[1] * stride;

        const float x1 = (cx - dx * 0.5f - MIN_Xf) / vx;
        const float x2 = (cx + dx * 0.5f - MIN_Xf) / vx;
        const float y1 = (cy - dy * 0.5f - MIN_Yf) / vy;
        const float y2 = (cy + dy * 0.5f - MIN_Yf) / vy;

        float sina, cosa;
        __sincosf(ang, &sina, &cosa);

        const float wm1 = (float)(Wc - 1);
        const float hm1 = (float)(Hc - 1);
        const float scale1 = (y2 - y1) / fmaxf(x2 - x1, 0.01f);
        const float scale2 = (x2 - x1) / fmaxf(y2 - y1, 0.01f);
        const float t00 = (x2 - x1) / wm1 * cosa;
        const float t01 = (x2 - x1) / wm1 * (-sina) * scale1;
        const float t02 = (x1 + x2 - wm1) / wm1;
        const float t10 = (y2 - y1) / hm1 * sina * scale2;
        const float t11 = (y2 - y1) / hm1 * cosa;
        const float t12 = (y1 + y2 - hm1) / hm1;

        const int row = tid / G;
        const int col = tid - row * G;
        // affine_grid base coords, align_corners=False
        const float xx = (2.0f * (float)col + 1.0f) / (float)G - 1.0f;
        const float yy = (2.0f * (float)row + 1.0f) / (float)G - 1.0f;
        const float gx = t00 * xx + t01 * yy + t02;
        const float gy = t10 * xx + t11 * yy + t12;
        // grid_sample unnormalize, align_corners=False
        const float ix = ((gx + 1.0f) * (float)Wc - 1.0f) * 0.5f;
        const float iy = ((gy + 1.0f) * (float)Hc - 1.0f) * 0.5f;

        const float x0f = floorf(ix);
        const float y0f = floorf(iy);
        const float x1f = x0f + 1.0f;
        const float y1f = y0f + 1.0f;
        const float wx1 = ix - x0f, wx0 = 1.0f - wx1;
        const float wy1 = iy - y0f, wy0 = 1.0f - wy1;

        const float vx0 = (x0f >= 0.0f && x0f <= wm1) ? 1.0f : 0.0f;
        const float vx1 = (x1f >= 0.0f && x1f <= wm1) ? 1.0f : 0.0f;
        const float vy0 = (y0f >= 0.0f && y0f <= hm1) ? 1.0f : 0.0f;
        const float vy1 = (y1f >= 0.0f && y1f <= hm1) ? 1.0f : 0.0f;

        const int xc0 = (int)fminf(fmaxf(x0f, 0.0f), wm1);
        const int xc1 = (int)fminf(fmaxf(x1f, 0.0f), wm1);
        const int yc0 = (int)fminf(fmaxf(y0f, 0.0f), hm1);
        const int yc1 = (int)fminf(fmaxf(y1f, 0.0f), hm1);

        s_o00[tid] = yc0 * Wc + xc0;
        s_o01[tid] = yc0 * Wc + xc1;
        s_o10[tid] = yc1 * Wc + xc0;
        s_o11[tid] = yc1 * Wc + xc1;
        s_w00[tid] = wy0 * wx0 * vy0 * vx0;
        s_w01[tid] = wy0 * wx1 * vy0 * vx1;
        s_w10[tid] = wy1 * wx0 * vy1 * vx0;
        s_w11[tid] = wy1 * wx1 * vy1 * vx1;
    }
    __syncthreads();

    // ---- main loop: 32 channels x 49 pts, coalesced writes ----
    const float* __restrict__ fb = feat + ((size_t)b * Cc + chunk * CCHUNK) * (Hc * Wc);
    float* __restrict__ ob = out + ((size_t)bn * Cc + chunk * CCHUNK) * NPTS;

    #pragma unroll
    for (int k = 0; k < 7; ++k) {
        const int e = tid + k * 256;
        if (e < ELEMS) {
            const int c  = e / NPTS;
            const int pt = e - c * NPTS;
            const float* __restrict__ fc = fb + (size_t)c * (Hc * Wc);
            const float v = s_w00[pt] * fc[s_o00[pt]]
                          + s_w01[pt] * fc[s_o01[pt]]
                          + s_w10[pt] * fc[s_o10[pt]]
                          + s_w11[pt] * fc[s_o11[pt]];
            ob[e] = v;
        }
    }
}

extern "C" void kernel_launch(void* const* d_in, const int* in_sizes, int n_in,
                              void* d_out, int out_size, void* d_ws, size_t ws_size,
                              hipStream_t stream) {
    const float* feat = (const float*)d_in[0];
    const float* rois = (const float*)d_in[1];
    const float* vox  = (const float*)d_in[2];
    const int*   fms  = (const int*)d_in[3];
    float* out = (float*)d_out;

    rot_grid_pool_kernel<<<dim3(Bc * Nc, CSPLIT), dim3(256), 0, stream>>>(
        feat, rois, vox, fms, out);
}

// Round 3
// 211.947 us; speedup vs baseline: 1.0321x; 1.0155x over previous
//
#include <hip/hip_runtime.h>

// RotatedGridPool: B=4, C=256, H=200, W=176, N=128, G=7
// Output: (B*N, C, G, G) fp32.
//
// R3: gathers are the bottleneck (TA address-processing on divergent loads).
// Merge the two x-adjacent corner loads per row into one dwordx2 gather:
// 4 divergent dword loads -> 2 divergent dwordx2 loads per output.
// Zero-padding / clamp edge cases are folded into 4 precomputed weights
// applying directly to {r0.x, r0.y, r1.x, r1.y}; loads always in-bounds.
// Per-point LDS data packed as int2 offsets + float4 weights (2 LDS reads).

constexpr int Bc = 4;
constexpr int Cc = 256;
constexpr int Hc = 200;
constexpr int Wc = 176;
constexpr int Nc = 128;
constexpr int G  = 7;
constexpr int NPTS = G * G;           // 49
constexpr int CSPLIT = 8;             // blocks per ROI
constexpr int CCHUNK = Cc / CSPLIT;   // 32 channels per block
constexpr int ELEMS  = CCHUNK * NPTS; // 1568
constexpr float MIN_Xf = 0.0f;
constexpr float MIN_Yf = -40.0f;

// 8-byte load with only 4-byte alignment guarantee (x-offset is arbitrary).
struct __attribute__((packed, aligned(4))) f2u { float x, y; };

__global__ __launch_bounds__(256, 8) void rot_grid_pool_kernel(
    const float* __restrict__ feat,       // (B,C,H,W)
    const float* __restrict__ rois,       // (B,N,7)
    const float* __restrict__ voxel_size, // (2,)
    const int*   __restrict__ fms,        // scalar stride
    float* __restrict__ out)              // (B*N, C, G, G)
{
    const int bn    = blockIdx.x;         // 0 .. B*N-1
    const int chunk = blockIdx.y;         // 0 .. CSPLIT-1
    const int b     = bn / Nc;

    __shared__ int2   s_off[NPTS];        // flat offsets of the two row loads
    __shared__ float4 s_wgt[NPTS];        // weights for r0.x, r0.y, r1.x, r1.y

    const int tid = threadIdx.x;
    if (tid < NPTS) {
        // ---- per-ROI affine theta ----
        const float* roi = rois + (size_t)bn * 7;
        const float cx = roi[0], cy = roi[1];
        const float dx = roi[3], dy = roi[4];
        const float ang = roi[6];
        const float stride = (float)fms[0];
        const float vx = voxel_size[0] * stride;
        const float vy = voxel_size[1] * stride;

        const float x1 = (cx - dx * 0.5f - MIN_Xf) / vx;
        const float x2 = (cx + dx * 0.5f - MIN_Xf) / vx;
        const float y1 = (cy - dy * 0.5f - MIN_Yf) / vy;
        const float y2 = (cy + dy * 0.5f - MIN_Yf) / vy;

        float sina, cosa;
        __sincosf(ang, &sina, &cosa);

        const float wm1 = (float)(Wc - 1);
        const float hm1 = (float)(Hc - 1);
        const float scale1 = (y2 - y1) / fmaxf(x2 - x1, 0.01f);
        const float scale2 = (x2 - x1) / fmaxf(y2 - y1, 0.01f);
        const float t00 = (x2 - x1) / wm1 * cosa;
        const float t01 = (x2 - x1) / wm1 * (-sina) * scale1;
        const float t02 = (x1 + x2 - wm1) / wm1;
        const float t10 = (y2 - y1) / hm1 * sina * scale2;
        const float t11 = (y2 - y1) / hm1 * cosa;
        const float t12 = (y1 + y2 - hm1) / hm1;

        const int row = tid / G;
        const int col = tid - row * G;
        const float xx = (2.0f * (float)col + 1.0f) / (float)G - 1.0f;
        const float yy = (2.0f * (float)row + 1.0f) / (float)G - 1.0f;
        const float gx = t00 * xx + t01 * yy + t02;
        const float gy = t10 * xx + t11 * yy + t12;
        const float ix = ((gx + 1.0f) * (float)Wc - 1.0f) * 0.5f;
        const float iy = ((gy + 1.0f) * (float)Hc - 1.0f) * 0.5f;

        const float x0f = floorf(ix);
        const float y0f = floorf(iy);
        const float wx1 = ix - x0f, wx0 = 1.0f - wx1;
        const float wy1 = iy - y0f, wy0 = 1.0f - wy1;

        const bool vx0 = (x0f >= 0.0f) && (x0f <= wm1);
        const bool vx1 = (x0f + 1.0f >= 0.0f) && (x0f + 1.0f <= wm1);
        const bool vy0 = (y0f >= 0.0f) && (y0f <= hm1);
        const bool vy1 = (y0f + 1.0f >= 0.0f) && (y0f + 1.0f <= hm1);

        const int x0i = (int)x0f;
        const int y0i = (int)y0f;
        const int xs  = min(max(x0i, 0), Wc - 2);   // dwordx2 at xs always in-bounds
        const int yc0 = min(max(y0i, 0), Hc - 1);
        const int yc1 = min(max(y0i + 1, 0), Hc - 1);

        // weights applying to f[xs] (wa) and f[xs+1] (wb), edge cases folded in
        const float wa = ((vx0 && x0i     == xs    ) ? wx0 : 0.0f)
                       + ((vx1 && x0i + 1 == xs    ) ? wx1 : 0.0f);
        const float wb = ((vx0 && x0i     == xs + 1) ? wx0 : 0.0f)
                       + ((vx1 && x0i + 1 == xs + 1) ? wx1 : 0.0f);
        const float rw0 = vy0 ? wy0 : 0.0f;
        const float rw1 = vy1 ? wy1 : 0.0f;

        s_off[tid] = make_int2(yc0 * Wc + xs, yc1 * Wc + xs);
        s_wgt[tid] = make_float4(rw0 * wa, rw0 * wb, rw1 * wa, rw1 * wb);
    }
    __syncthreads();

    const float* __restrict__ fb = feat + ((size_t)b * Cc + chunk * CCHUNK) * (Hc * Wc);
    float* __restrict__ ob = out + ((size_t)bn * Cc + chunk * CCHUNK) * NPTS;

    #pragma unroll
    for (int k = 0; k < 7; ++k) {
        const int e = tid + k * 256;
        if (e < ELEMS) {
            const int c  = e / NPTS;
            const int pt = e - c * NPTS;
            const float* __restrict__ fc = fb + (size_t)c * (Hc * Wc);
            const int2   o = s_off[pt];
            const float4 w = s_wgt[pt];
            const f2u r0 = *(const f2u*)(fc + o.x);
            const f2u r1 = *(const f2u*)(fc + o.y);
            ob[e] = w.x * r0.x + w.y * r0.y + w.z * r1.x + w.w * r1.y;
        }
    }
}

extern "C" void kernel_launch(void* const* d_in, const int* in_sizes, int n_in,
                              void* d_out, int out_size, void* d_ws, size_t ws_size,
                              hipStream_t stream) {
    const float* feat = (const float*)d_in[0];
    const float* rois = (const float*)d_in[1];
    const float* vox  = (const float*)d_in[2];
    const int*   fms  = (const int*)d_in[3];
    float* out = (float*)d_out;

    rot_grid_pool_kernel<<<dim3(Bc * Nc, CSPLIT), dim3(256), 0, stream>>>(
        feat, rois, vox, fms, out);
}